// Round 7
// baseline (493.030 us; speedup 1.0000x reference)
//
#include <hip/hip_runtime.h>
#include <hip/hip_bf16.h>

typedef short bf16x8 __attribute__((ext_vector_type(8)));
typedef float f32x4 __attribute__((ext_vector_type(4)));
typedef unsigned short u16;

#define LOG2E 1.44269504088896340736f

__device__ __forceinline__ u16 f2bf(float f) {
    unsigned u = __float_as_uint(f);
    u += 0x7fffu + ((u >> 16) & 1u);   // round-to-nearest-even
    return (u16)(u >> 16);
}
__device__ __forceinline__ float bf2f(u16 h) {
    return __uint_as_float(((unsigned)h) << 16);
}

// ---------------------------------------------------------------------------
// Kernel 0: weight prep. Combined rows: [0,256)=Wv, [256,288)=Wq*log2e, [288,320)=Wk.
// Split each f32 weight into bf16 hi + bf16 lo. Combined bias (q-bias pre-scaled).
// ---------------------------------------------------------------------------
__global__ void k_prep(const float* __restrict__ Wq, const float* __restrict__ bq,
                       const float* __restrict__ Wk, const float* __restrict__ bk,
                       const float* __restrict__ Wv, const float* __restrict__ bv,
                       u16* __restrict__ Whi, u16* __restrict__ Wlo,
                       float* __restrict__ bias) {
    int idx = blockIdx.x * 256 + threadIdx.x;
    if (idx >= 320 * 256) return;
    int row = idx >> 8, c = idx & 255;
    float w, b;
    if (row < 256)      { w = Wv[row * 256 + c];                  b = bv[row]; }
    else if (row < 288) { w = Wq[(row - 256) * 256 + c] * LOG2E;  b = bq[row - 256] * LOG2E; }
    else                { w = Wk[(row - 288) * 256 + c];          b = bk[row - 288]; }
    u16 hi = f2bf(w);
    Whi[idx] = hi;
    Wlo[idx] = f2bf(w - bf2f(hi));
    if (c == 0) bias[row] = b;
}

// ---------------------------------------------------------------------------
// Kernel 1: fused QKV projection. out[320 rows][4096 n] per batch via MFMA.
// 3-term split product: Whi*xhi + Whi*xlo + Wlo*xhi  (~fp32 accuracy).
// Writes: vbf[b][256][4096] bf16 ; qt/kt[b][4096][64] bf16 (cols 0..31 hi, 32..63 lo)
// ---------------------------------------------------------------------------
#define XPAD 264  // xT row stride in elems (=528B, 16B-multiple, conflict-friendly)

__global__ __launch_bounds__(256) void k_proj(
    const float* __restrict__ x, const u16* __restrict__ Whi,
    const u16* __restrict__ Wlo, const float* __restrict__ bias,
    u16* __restrict__ qt, u16* __restrict__ kt, u16* __restrict__ vbf) {
    __shared__ __attribute__((aligned(16))) u16 xh[64 * XPAD];
    __shared__ __attribute__((aligned(16))) u16 xl[64 * XPAD];
    int bid = blockIdx.x;
    int b = bid & 7, nt = bid >> 3;
    int n0 = nt * 64;
    int t = threadIdx.x;
    int lane = t & 63, w = t >> 6;
    int lr = lane & 15, lk = lane >> 4;

    // ---- stage x tile transposed + bf16-split into LDS ----
    {
        int n = t & 63;
        int cg = t >> 6;
        for (int it = 0; it < 8; ++it) {
            int c8 = (it * 4 + cg) * 8;
            bf16x8 hv, lv;
#pragma unroll
            for (int u = 0; u < 8; ++u) {
                float xv = x[((size_t)(b * 256 + c8 + u)) * 4096 + n0 + n];
                u16 hu = f2bf(xv);
                hv[u] = (short)hu;
                lv[u] = (short)f2bf(xv - bf2f(hu));
            }
            *(bf16x8*)&xh[n * XPAD + c8] = hv;
            *(bf16x8*)&xl[n * XPAD + c8] = lv;
        }
    }
    __syncthreads();

    f32x4 acc[5][4];
#pragma unroll
    for (int i = 0; i < 5; i++)
#pragma unroll
        for (int j = 0; j < 4; j++) acc[i][j] = (f32x4){0.f, 0.f, 0.f, 0.f};

    for (int cs = 0; cs < 8; ++cs) {
        int c0 = cs * 32;
        bf16x8 ah[5], al[5], bh[4], bl[4];
#pragma unroll
        for (int mt = 0; mt < 5; ++mt) {
            int row = (w * 5 + mt) * 16 + lr;
            ah[mt] = *(const bf16x8*)&Whi[row * 256 + c0 + lk * 8];
            al[mt] = *(const bf16x8*)&Wlo[row * 256 + c0 + lk * 8];
        }
#pragma unroll
        for (int ns = 0; ns < 4; ++ns) {
            int np = ns * 16 + lr;
            bh[ns] = *(const bf16x8*)&xh[np * XPAD + c0 + lk * 8];
            bl[ns] = *(const bf16x8*)&xl[np * XPAD + c0 + lk * 8];
        }
#pragma unroll
        for (int mt = 0; mt < 5; ++mt)
#pragma unroll
            for (int ns = 0; ns < 4; ++ns) {
                acc[mt][ns] = __builtin_amdgcn_mfma_f32_16x16x32_bf16(ah[mt], bh[ns], acc[mt][ns], 0, 0, 0);
                acc[mt][ns] = __builtin_amdgcn_mfma_f32_16x16x32_bf16(ah[mt], bl[ns], acc[mt][ns], 0, 0, 0);
                acc[mt][ns] = __builtin_amdgcn_mfma_f32_16x16x32_bf16(al[mt], bh[ns], acc[mt][ns], 0, 0, 0);
            }
    }

    // ---- epilogue: bias + scatter to v / q(hi,lo) / k(hi,lo) ----
#pragma unroll
    for (int mt = 0; mt < 5; ++mt) {
        int tile = w * 5 + mt;  // 0..19 ; 16-row tiles never straddle v/q/k regions
#pragma unroll
        for (int ns = 0; ns < 4; ++ns) {
#pragma unroll
            for (int r = 0; r < 4; ++r) {
                int row = tile * 16 + lk * 4 + r;
                int n = n0 + ns * 16 + lr;
                float val = acc[mt][ns][r] + bias[row];
                if (row < 256) {
                    vbf[((size_t)(b * 256 + row)) * 4096 + n] = f2bf(val);
                } else if (row < 288) {
                    u16 hi = f2bf(val);
                    size_t base = ((size_t)(b * 4096 + n)) * 64 + (row - 256);
                    qt[base] = hi;
                    qt[base + 32] = f2bf(val - bf2f(hi));
                } else {
                    u16 hi = f2bf(val);
                    size_t base = ((size_t)(b * 4096 + n)) * 64 + (row - 288);
                    kt[base] = hi;
                    kt[base + 32] = f2bf(val - bf2f(hi));
                }
            }
        }
    }
}

// ---------------------------------------------------------------------------
// Kernel 1.5: per-batch safety shift. Cauchy-Schwarz bound on scores:
// |s| <= ||q||max * ||k||max (q already carries log2e). shift = max(0, B-80):
// normally 0 -> P = exp2(s) exactly (softmax is shift-invariant; f32 exp2
// overflows only past 2^127, L/acc stay < 2^100). Norms from hi parts only.
// ---------------------------------------------------------------------------
__global__ __launch_bounds__(256) void k_bound(
    const u16* __restrict__ qt, const u16* __restrict__ kt,
    float* __restrict__ Sh) {
    __shared__ float rq[4], rk[4];
    int b = blockIdx.x;
    int t = threadIdx.x;
    int lane = t & 63, w = t >> 6;
    float qm = 0.f, km = 0.f;
    for (int n = t; n < 4096; n += 256) {
        size_t base = ((size_t)(b * 4096 + n)) * 64;
        float sq = 0.f, sk = 0.f;
#pragma unroll
        for (int g = 0; g < 4; ++g) {
            bf16x8 vq = *(const bf16x8*)&qt[base + g * 8];
            bf16x8 vk = *(const bf16x8*)&kt[base + g * 8];
#pragma unroll
            for (int u = 0; u < 8; ++u) {
                float a = bf2f((u16)vq[u]), c = bf2f((u16)vk[u]);
                sq += a * a;
                sk += c * c;
            }
        }
        qm = fmaxf(qm, sq);
        km = fmaxf(km, sk);
    }
#pragma unroll
    for (int d = 1; d < 64; d <<= 1) {
        qm = fmaxf(qm, __shfl_xor(qm, d));
        km = fmaxf(km, __shfl_xor(km, d));
    }
    if (lane == 0) { rq[w] = qm; rk[w] = km; }
    __syncthreads();
    if (t == 0) {
        float a = fmaxf(fmaxf(rq[0], rq[1]), fmaxf(rq[2], rq[3]));
        float c = fmaxf(fmaxf(rk[0], rk[1]), fmaxf(rk[2], rk[3]));
        // qt already scaled by log2e, so sqrt(a)*sqrt(c) IS the log2 bound
        Sh[b] = fmaxf(0.f, sqrtf(a) * sqrtf(c) - 80.f);
    }
}

// ---------------------------------------------------------------------------
// Kernel 2: attention as tiled GEMM with on-the-fly P = exp2(s - shift).
// No max tracking, no rescale, no cross-iteration softmax state; L summed
// inline per lane. Block = 32 j-cols, 4 waves, grid 1024 -> 4 blocks/CU
// (16 waves/CU, 2x round-6 TLP). Wave w: produces P-piece (js=w&1, i-half
// w>>1) of the 64-i tile AND PVs c-chunk w*64 over all 64 i x 32 j.
// Double-buffered P, ONE barrier per 64-i tile; av issued pre-barrier
// (drained by the barrier), q prefetched post-barrier under PV. Output f32.
// ---------------------------------------------------------------------------
#define PSTR 72  // P row stride in u16: 64 i + pad; 144B rows (16B-aligned)

__global__ __launch_bounds__(256, 4) void k_attn(
    const u16* __restrict__ qt, const u16* __restrict__ kt,
    const u16* __restrict__ vbf, const float* __restrict__ Sh,
    const float* __restrict__ x, const float* __restrict__ gamma,
    float* __restrict__ out) {
    __shared__ __attribute__((aligned(16))) u16 P[2][2][16][PSTR];  // 9.2 KB
    __shared__ float Ls[4][16];
    int bid = blockIdx.x;
    int b = bid & 7, jt = bid >> 3;  // b = bid%8 pins batch -> XCD (L2 locality)
    int t = threadIdx.x;
    int lane = t & 63, w = t >> 6;
    int lr = lane & 15, lk = lane >> 4;
    int j0 = jt * 32;
    int js = w & 1, ih = w >> 1;     // P-production role: j-subtile, i-half

    // K fragments for production j-subtile (hi and lo parts), loaded once
    size_t kb = ((size_t)(b * 4096 + j0 + js * 16 + lr)) * 64 + lk * 8;
    bf16x8 khi = *(const bf16x8*)&kt[kb];
    bf16x8 klo = *(const bf16x8*)&kt[kb + 32];
    float shift = Sh[b];             // usually 0.0f

    f32x4 acc[4][2];   // [ct][js2]: c = w*64+ct*16+lk*4+r , j = j0+js2*16+lr
#pragma unroll
    for (int i = 0; i < 4; i++)
#pragma unroll
        for (int j = 0; j < 2; j++) acc[i][j] = (f32x4){0.f, 0.f, 0.f, 0.f};
    float lsum = 0.f;
    const f32x4 zero = {0.f, 0.f, 0.f, 0.f};

    // one pipeline step: QK(q_cur) -> P[p] -> av loads -> barrier -> q_next
    // loads (covered by PV) -> PV(av, P[p]).
    auto step = [&](int p, int itc, bf16x8 (&qh)[2], bf16x8 (&ql)[2],
                    bf16x8 (&qhn)[2], bf16x8 (&qln)[2]) {
        int i0 = itc * 64;
        // QK^T (3-term split) for own 32 i-rows (i-half ih) of own 16 cols
        f32x4 s[2];
#pragma unroll
        for (int g = 0; g < 2; ++g) {
            s[g] = __builtin_amdgcn_mfma_f32_16x16x32_bf16(qh[g], khi, zero, 0, 0, 0);
            s[g] = __builtin_amdgcn_mfma_f32_16x16x32_bf16(qh[g], klo, s[g], 0, 0, 0);
            s[g] = __builtin_amdgcn_mfma_f32_16x16x32_bf16(ql[g], khi, s[g], 0, 0, 0);
        }
        // P = exp2(s - shift); accumulate L inline; pack to bf16; write piece
#pragma unroll
        for (int g = 0; g < 2; ++g) {
            float p0 = exp2f(s[g][0] - shift), p1 = exp2f(s[g][1] - shift);
            float p2 = exp2f(s[g][2] - shift), p3 = exp2f(s[g][3] - shift);
            lsum += (p0 + p1) + (p2 + p3);
            uint2 pk;
            pk.x = ((unsigned)f2bf(p1) << 16) | f2bf(p0);
            pk.y = ((unsigned)f2bf(p3) << 16) | f2bf(p2);
            // P[p][js][j_local=lr][i_local = ih*32 + g*16 + lk*4 + 0..3]
            *(uint2*)&P[p][js][lr][ih * 32 + g * 16 + lk * 4] = pk;
        }
        // v loads for THIS step (drained by the barrier's vmcnt wait)
        bf16x8 av[8];
#pragma unroll
        for (int ks = 0; ks < 2; ++ks)
#pragma unroll
            for (int ct = 0; ct < 4; ++ct)
                av[ks * 4 + ct] = *(const bf16x8*)&vbf[((size_t)(b * 256 + w * 64 + ct * 16 + lr)) * 4096
                                                       + i0 + ks * 32 + lk * 8];
        __syncthreads();   // publishes P[p]; drains av loads
        // q prefetch for next step (latency covered by PV below)
        int i0n = ((itc + 1) & 63) * 64;   // wraps 64->0: harmless reload
#pragma unroll
        for (int g = 0; g < 2; ++g) {
            size_t qb = ((size_t)(b * 4096 + i0n + ih * 32 + g * 16 + lr)) * 64 + lk * 8;
            qhn[g] = *(const bf16x8*)&qt[qb];
            qln[g] = *(const bf16x8*)&qt[qb + 32];
        }
        // PV: acc[c, j] += v[c, i-tile] * P[i-tile, j]  (own 64-c chunk)
#pragma unroll
        for (int ks = 0; ks < 2; ++ks) {
            bf16x8 bp[2];
#pragma unroll
            for (int j2 = 0; j2 < 2; ++j2)
                bp[j2] = *(const bf16x8*)&P[p][j2][lr][ks * 32 + lk * 8];
#pragma unroll
            for (int ct = 0; ct < 4; ++ct)
#pragma unroll
                for (int j2 = 0; j2 < 2; ++j2)
                    acc[ct][j2] = __builtin_amdgcn_mfma_f32_16x16x32_bf16(av[ks * 4 + ct], bp[j2], acc[ct][j2], 0, 0, 0);
        }
    };

    // prologue: load q for it=0
    bf16x8 qhA[2], qlA[2], qhB[2], qlB[2];
#pragma unroll
    for (int g = 0; g < 2; ++g) {
        size_t qb = ((size_t)(b * 4096 + ih * 32 + g * 16 + lr)) * 64 + lk * 8;
        qhA[g] = *(const bf16x8*)&qt[qb];
        qlA[g] = *(const bf16x8*)&qt[qb + 32];
    }
    for (int it = 0; it < 64; it += 2) {
        step(0, it,     qhA, qlA, qhB, qlB);
        step(1, it + 1, qhB, qlB, qhA, qlA);
    }

    // ---- epilogue: combine per-lane L partials, normalize, residual ----
    lsum += __shfl_xor(lsum, 16);
    lsum += __shfl_xor(lsum, 32);     // lanes with same lr now hold wave sum
    if (lane < 16) Ls[w][lr] = lsum;  // column (js, lr), i-half ih
    __syncthreads();
    float g = gamma[0];
    float linv[2];
#pragma unroll
    for (int j2 = 0; j2 < 2; ++j2)
        linv[j2] = g / (Ls[j2][lr] + Ls[j2 + 2][lr]);  // ih=0 + ih=1 partials
#pragma unroll
    for (int ct = 0; ct < 4; ++ct)
#pragma unroll
        for (int r = 0; r < 4; ++r) {
            int c = w * 64 + ct * 16 + lk * 4 + r;
            size_t base = ((size_t)(b * 256 + c)) * 4096 + j0;
#pragma unroll
            for (int j2 = 0; j2 < 2; ++j2) {
                int j = j2 * 16 + lr;
                out[base + j] = acc[ct][j2][r] * linv[j2] + x[base + j];
            }
        }
}

// ---------------------------------------------------------------------------
extern "C" void kernel_launch(void* const* d_in, const int* in_sizes, int n_in,
                              void* d_out, int out_size, void* d_ws, size_t ws_size,
                              hipStream_t stream) {
    const float* x = (const float*)d_in[0];
    const float* Wq = (const float*)d_in[1];
    const float* bq = (const float*)d_in[2];
    const float* Wk = (const float*)d_in[3];
    const float* bk = (const float*)d_in[4];
    const float* Wv = (const float*)d_in[5];
    const float* bv = (const float*)d_in[6];
    const float* gamma = (const float*)d_in[7];

    char* ws = (char*)d_ws;
    u16* Whi = (u16*)ws;                               // 163840 B
    u16* Wlo = (u16*)(ws + 163840);                    // 163840 B
    float* bias = (float*)(ws + 327680);               // 1280 B
    u16* qt = (u16*)(ws + 329216);                     // 4 MB  [8][4096][64]
    u16* kt = (u16*)(ws + 329216 + 4194304);           // 4 MB
    u16* vbf = (u16*)(ws + 329216 + 8388608);          // 16 MB [8][256][4096]
    float* Shf = (float*)(ws + 329216 + 25165824);     // 32 B  [8]
    // total ws use ~25.5 MB

    k_prep<<<320, 256, 0, stream>>>(Wq, bq, Wk, bk, Wv, bv, Whi, Wlo, bias);
    k_proj<<<512, 256, 0, stream>>>(x, Whi, Wlo, bias, qt, kt, vbf);
    k_bound<<<8, 256, 0, stream>>>(qt, kt, Shf);
    k_attn<<<1024, 256, 0, stream>>>(qt, kt, vbf, Shf, x, gamma, (float*)d_out);
}

// Round 8
// 300.844 us; speedup vs baseline: 1.6388x; 1.6388x over previous
//
#include <hip/hip_runtime.h>
#include <hip/hip_bf16.h>

typedef short bf16x8 __attribute__((ext_vector_type(8)));
typedef float f32x4 __attribute__((ext_vector_type(4)));
typedef unsigned short u16;

#define LOG2E 1.44269504088896340736f
#define AS1 __attribute__((address_space(1)))
#define AS3 __attribute__((address_space(3)))

__device__ __forceinline__ u16 f2bf(float f) {
    unsigned u = __float_as_uint(f);
    u += 0x7fffu + ((u >> 16) & 1u);   // round-to-nearest-even
    return (u16)(u >> 16);
}
__device__ __forceinline__ float bf2f(u16 h) {
    return __uint_as_float(((unsigned)h) << 16);
}
// async global->LDS, 16B/lane. LDS dest is WAVE-UNIFORM base; HW adds lane*16.
__device__ __forceinline__ void gload_lds16(const void* g, void* l) {
    __builtin_amdgcn_global_load_lds((const AS1 unsigned int*)g,
                                     (AS3 unsigned int*)l, 16, 0, 0);
}

// ---------------------------------------------------------------------------
// Kernel 0: weight prep. Combined rows: [0,256)=Wv, [256,288)=Wq*log2e, [288,320)=Wk.
// ---------------------------------------------------------------------------
__global__ void k_prep(const float* __restrict__ Wq, const float* __restrict__ bq,
                       const float* __restrict__ Wk, const float* __restrict__ bk,
                       const float* __restrict__ Wv, const float* __restrict__ bv,
                       u16* __restrict__ Whi, u16* __restrict__ Wlo,
                       float* __restrict__ bias) {
    int idx = blockIdx.x * 256 + threadIdx.x;
    if (idx >= 320 * 256) return;
    int row = idx >> 8, c = idx & 255;
    float w, b;
    if (row < 256)      { w = Wv[row * 256 + c];                  b = bv[row]; }
    else if (row < 288) { w = Wq[(row - 256) * 256 + c] * LOG2E;  b = bq[row - 256] * LOG2E; }
    else                { w = Wk[(row - 288) * 256 + c];          b = bk[row - 288]; }
    u16 hi = f2bf(w);
    Whi[idx] = hi;
    Wlo[idx] = f2bf(w - bf2f(hi));
    if (c == 0) bias[row] = b;
}

// ---------------------------------------------------------------------------
// Kernel 1: fused QKV projection (unchanged).
// ---------------------------------------------------------------------------
#define XPAD 264

__global__ __launch_bounds__(256) void k_proj(
    const float* __restrict__ x, const u16* __restrict__ Whi,
    const u16* __restrict__ Wlo, const float* __restrict__ bias,
    u16* __restrict__ qt, u16* __restrict__ kt, u16* __restrict__ vbf) {
    __shared__ __attribute__((aligned(16))) u16 xh[64 * XPAD];
    __shared__ __attribute__((aligned(16))) u16 xl[64 * XPAD];
    int bid = blockIdx.x;
    int b = bid & 7, nt = bid >> 3;
    int n0 = nt * 64;
    int t = threadIdx.x;
    int lane = t & 63, w = t >> 6;
    int lr = lane & 15, lk = lane >> 4;

    {
        int n = t & 63;
        int cg = t >> 6;
        for (int it = 0; it < 8; ++it) {
            int c8 = (it * 4 + cg) * 8;
            bf16x8 hv, lv;
#pragma unroll
            for (int u = 0; u < 8; ++u) {
                float xv = x[((size_t)(b * 256 + c8 + u)) * 4096 + n0 + n];
                u16 hu = f2bf(xv);
                hv[u] = (short)hu;
                lv[u] = (short)f2bf(xv - bf2f(hu));
            }
            *(bf16x8*)&xh[n * XPAD + c8] = hv;
            *(bf16x8*)&xl[n * XPAD + c8] = lv;
        }
    }
    __syncthreads();

    f32x4 acc[5][4];
#pragma unroll
    for (int i = 0; i < 5; i++)
#pragma unroll
        for (int j = 0; j < 4; j++) acc[i][j] = (f32x4){0.f, 0.f, 0.f, 0.f};

    for (int cs = 0; cs < 8; ++cs) {
        int c0 = cs * 32;
        bf16x8 ah[5], al[5], bh[4], bl[4];
#pragma unroll
        for (int mt = 0; mt < 5; ++mt) {
            int row = (w * 5 + mt) * 16 + lr;
            ah[mt] = *(const bf16x8*)&Whi[row * 256 + c0 + lk * 8];
            al[mt] = *(const bf16x8*)&Wlo[row * 256 + c0 + lk * 8];
        }
#pragma unroll
        for (int ns = 0; ns < 4; ++ns) {
            int np = ns * 16 + lr;
            bh[ns] = *(const bf16x8*)&xh[np * XPAD + c0 + lk * 8];
            bl[ns] = *(const bf16x8*)&xl[np * XPAD + c0 + lk * 8];
        }
#pragma unroll
        for (int mt = 0; mt < 5; ++mt)
#pragma unroll
            for (int ns = 0; ns < 4; ++ns) {
                acc[mt][ns] = __builtin_amdgcn_mfma_f32_16x16x32_bf16(ah[mt], bh[ns], acc[mt][ns], 0, 0, 0);
                acc[mt][ns] = __builtin_amdgcn_mfma_f32_16x16x32_bf16(ah[mt], bl[ns], acc[mt][ns], 0, 0, 0);
                acc[mt][ns] = __builtin_amdgcn_mfma_f32_16x16x32_bf16(al[mt], bh[ns], acc[mt][ns], 0, 0, 0);
            }
    }

#pragma unroll
    for (int mt = 0; mt < 5; ++mt) {
        int tile = w * 5 + mt;
#pragma unroll
        for (int ns = 0; ns < 4; ++ns) {
#pragma unroll
            for (int r = 0; r < 4; ++r) {
                int row = tile * 16 + lk * 4 + r;
                int n = n0 + ns * 16 + lr;
                float val = acc[mt][ns][r] + bias[row];
                if (row < 256) {
                    vbf[((size_t)(b * 256 + row)) * 4096 + n] = f2bf(val);
                } else if (row < 288) {
                    u16 hi = f2bf(val);
                    size_t base = ((size_t)(b * 4096 + n)) * 64 + (row - 256);
                    qt[base] = hi;
                    qt[base + 32] = f2bf(val - bf2f(hi));
                } else {
                    u16 hi = f2bf(val);
                    size_t base = ((size_t)(b * 4096 + n)) * 64 + (row - 288);
                    kt[base] = hi;
                    kt[base + 32] = f2bf(val - bf2f(hi));
                }
            }
        }
    }
}

// ---------------------------------------------------------------------------
// Kernel 1.5: per-batch safety shift (Cauchy-Schwarz bound), unchanged.
// ---------------------------------------------------------------------------
__global__ __launch_bounds__(256) void k_bound(
    const u16* __restrict__ qt, const u16* __restrict__ kt,
    float* __restrict__ Sh) {
    __shared__ float rq[4], rk[4];
    int b = blockIdx.x;
    int t = threadIdx.x;
    int lane = t & 63, w = t >> 6;
    float qm = 0.f, km = 0.f;
    for (int n = t; n < 4096; n += 256) {
        size_t base = ((size_t)(b * 4096 + n)) * 64;
        float sq = 0.f, sk = 0.f;
#pragma unroll
        for (int g = 0; g < 4; ++g) {
            bf16x8 vq = *(const bf16x8*)&qt[base + g * 8];
            bf16x8 vk = *(const bf16x8*)&kt[base + g * 8];
#pragma unroll
            for (int u = 0; u < 8; ++u) {
                float a = bf2f((u16)vq[u]), c = bf2f((u16)vk[u]);
                sq += a * a;
                sk += c * c;
            }
        }
        qm = fmaxf(qm, sq);
        km = fmaxf(km, sk);
    }
#pragma unroll
    for (int d = 1; d < 64; d <<= 1) {
        qm = fmaxf(qm, __shfl_xor(qm, d));
        km = fmaxf(km, __shfl_xor(km, d));
    }
    if (lane == 0) { rq[w] = qm; rk[w] = km; }
    __syncthreads();
    if (t == 0) {
        float a = fmaxf(fmaxf(rq[0], rq[1]), fmaxf(rq[2], rq[3]));
        float c = fmaxf(fmaxf(rk[0], rk[1]), fmaxf(rk[2], rk[3]));
        Sh[b] = fmaxf(0.f, sqrtf(a) * sqrtf(c) - 80.f);
    }
}

// ---------------------------------------------------------------------------
// Kernel 2: LDS-STAGED attention GEMM (m97/T3 structure).
// j-tile 64, i-tile 32, 4 waves, grid 512. Per iter: STAGE(next q,v via
// global_load_lds, linear LDS dest, inverse-swizzled SOURCE) -> QK (q from
// LDS, swizzled read) -> P=exp2(s-shift) pack -> av ds_read (swizzled) ->
// barrier (drains stage) -> PV. Double-buffered q/v/P; ONE barrier/iter.
// Swizzles (all verified 2-way-max bank aliasing = free):
//   q row 128B, 8 slots:  phys_slot = logical ^ (row&7)
//   v row  64B, 4 slots:  phys_slot = logical ^ ((row>>1)&3)
//   P row stride 40 u16 (80B): naturally 2-way. Output f32.
// ---------------------------------------------------------------------------
#define PSTR 40

__global__ __launch_bounds__(256) void k_attn(
    const u16* __restrict__ qt, const u16* __restrict__ kt,
    const u16* __restrict__ vbf, const float* __restrict__ Sh,
    const float* __restrict__ x, const float* __restrict__ gamma,
    float* __restrict__ out) {
    __shared__ __attribute__((aligned(16))) u16 qlds[2][32 * 64];    //  8 KB
    __shared__ __attribute__((aligned(16))) u16 vlds[2][256 * 32];   // 32 KB
    __shared__ __attribute__((aligned(16))) u16 P[2][4][16][PSTR];   // 10 KB
    __shared__ float Ls[4][16];
    int bid = blockIdx.x;
    int b = bid & 7, jt = bid >> 3;  // b = bid%8 pins batch -> XCD (L2 locality)
    int t = threadIdx.x;
    int lane = t & 63, w = t >> 6;
    int lr = lane & 15, lk = lane >> 4;
    int j0 = jt * 64;

    // K fragments for this wave's production j-subtile (js = w), loaded once
    size_t kb = ((size_t)(b * 4096 + j0 + w * 16 + lr)) * 64 + lk * 8;
    bf16x8 khi = *(const bf16x8*)&kt[kb];
    bf16x8 klo = *(const bf16x8*)&kt[kb + 32];
    float shift = Sh[b];

    // stage i-tile [i0, i0+32) into buffer nb. LDS dest uniform; source
    // pre-swizzled so (LDS phys slot) = (logical slot) ^ (row-derived xor).
    auto stage = [&](int nb, int i0) {
        // v: 16 KB = 16 wave-issues of 1 KB; wave w does I = w*4..w*4+3
#pragma unroll
        for (int n = 0; n < 4; ++n) {
            int I = w * 4 + n;
            int c = I * 16 + (lane >> 2);                  // lane covers 16B = slot
            int s = (lane & 3) ^ ((lane >> 3) & 3);        // logical slot for this phys
            gload_lds16(vbf + ((size_t)(b * 256 + c)) * 4096 + i0 + s * 8,
                        &vlds[nb][I * 512]);
        }
        // q: 4 KB = 4 wave-issues; wave w does issue w (rows w*8..w*8+7)
        {
            int i = w * 8 + (lane >> 3);
            int s = (lane & 7) ^ ((lane >> 3) & 7);
            gload_lds16(qt + ((size_t)(b * 4096 + i0 + i)) * 64 + s * 8,
                        &qlds[nb][w * 512]);
        }
    };

    f32x4 acc[4][4];   // [ct][js]: c = w*64+ct*16+lk*4+r , j = j0+js*16+lr
#pragma unroll
    for (int i = 0; i < 4; i++)
#pragma unroll
        for (int j = 0; j < 4; j++) acc[i][j] = (f32x4){0.f, 0.f, 0.f, 0.f};
    float lsum = 0.f;
    const f32x4 zero = {0.f, 0.f, 0.f, 0.f};

    // prologue: stage tile 0, wait for it
    stage(0, 0);
    __syncthreads();   // compiler emits vmcnt(0) drain before barrier

    for (int it = 0; it < 128; ++it) {
        int buf = it & 1;
        // issue next tile's staging NOW; latency hidden under QK/exp below
        stage(buf ^ 1, ((it + 1) & 127) * 32);

        // ---- QK^T from LDS (swizzled q reads): own 16 j x 32 i ----
        bf16x8 qh[2], ql[2];
#pragma unroll
        for (int g = 0; g < 2; ++g) {
            int i = g * 16 + lr;
            int ph = lk ^ (lr & 7);                        // hi phys slot
            qh[g] = *(const bf16x8*)&qlds[buf][i * 64 + ph * 8];
            ql[g] = *(const bf16x8*)&qlds[buf][i * 64 + (ph ^ 4) * 8];
        }
        f32x4 s[2];
#pragma unroll
        for (int g = 0; g < 2; ++g) {
            s[g] = __builtin_amdgcn_mfma_f32_16x16x32_bf16(qh[g], khi, zero, 0, 0, 0);
            s[g] = __builtin_amdgcn_mfma_f32_16x16x32_bf16(qh[g], klo, s[g], 0, 0, 0);
            s[g] = __builtin_amdgcn_mfma_f32_16x16x32_bf16(ql[g], khi, s[g], 0, 0, 0);
        }

        // ---- P = exp2(s - shift); inline L; pack bf16; write P[buf] ----
#pragma unroll
        for (int g = 0; g < 2; ++g) {
            float p0 = exp2f(s[g][0] - shift), p1 = exp2f(s[g][1] - shift);
            float p2 = exp2f(s[g][2] - shift), p3 = exp2f(s[g][3] - shift);
            lsum += (p0 + p1) + (p2 + p3);
            uint2 pk;
            pk.x = ((unsigned)f2bf(p1) << 16) | f2bf(p0);
            pk.y = ((unsigned)f2bf(p3) << 16) | f2bf(p2);
            *(uint2*)&P[buf][w][lr][g * 16 + lk * 4] = pk;
        }

        // ---- av from LDS (swizzled v reads), own 64-c chunk ----
        bf16x8 av[4];
#pragma unroll
        for (int ct = 0; ct < 4; ++ct) {
            int c = w * 64 + ct * 16 + lr;
            int ph = lk ^ ((lr >> 1) & 3);
            av[ct] = *(const bf16x8*)&vlds[buf][c * 32 + ph * 8];
        }

        __syncthreads();   // publishes P[buf]; drains next-tile staging

        // ---- PV: acc[c, j] += v[c, i-tile] * P[i-tile, j] ----
        bf16x8 bp[4];
#pragma unroll
        for (int js = 0; js < 4; ++js)
            bp[js] = *(const bf16x8*)&P[buf][js][lr][lk * 8];
#pragma unroll
        for (int ct = 0; ct < 4; ++ct)
#pragma unroll
            for (int js = 0; js < 4; ++js)
                acc[ct][js] = __builtin_amdgcn_mfma_f32_16x16x32_bf16(av[ct], bp[js], acc[ct][js], 0, 0, 0);
    }

    // ---- epilogue: combine per-lane L partials, normalize, residual ----
    lsum += __shfl_xor(lsum, 16);
    lsum += __shfl_xor(lsum, 32);     // full column sum for column (w, lr)
    if (lane < 16) Ls[w][lr] = lsum;
    __syncthreads();
    float g = gamma[0];
    float linv[4];
#pragma unroll
    for (int js = 0; js < 4; ++js) linv[js] = g / Ls[js][lr];
#pragma unroll
    for (int ct = 0; ct < 4; ++ct)
#pragma unroll
        for (int r = 0; r < 4; ++r) {
            int c = w * 64 + ct * 16 + lk * 4 + r;
            size_t base = ((size_t)(b * 256 + c)) * 4096 + j0;
#pragma unroll
            for (int js = 0; js < 4; ++js) {
                int j = js * 16 + lr;
                out[base + j] = acc[ct][js][r] * linv[js] + x[base + j];
            }
        }
}

// ---------------------------------------------------------------------------
extern "C" void kernel_launch(void* const* d_in, const int* in_sizes, int n_in,
                              void* d_out, int out_size, void* d_ws, size_t ws_size,
                              hipStream_t stream) {
    const float* x = (const float*)d_in[0];
    const float* Wq = (const float*)d_in[1];
    const float* bq = (const float*)d_in[2];
    const float* Wk = (const float*)d_in[3];
    const float* bk = (const float*)d_in[4];
    const float* Wv = (const float*)d_in[5];
    const float* bv = (const float*)d_in[6];
    const float* gamma = (const float*)d_in[7];

    char* ws = (char*)d_ws;
    u16* Whi = (u16*)ws;                               // 163840 B
    u16* Wlo = (u16*)(ws + 163840);                    // 163840 B
    float* bias = (float*)(ws + 327680);               // 1280 B
    u16* qt = (u16*)(ws + 329216);                     // 4 MB  [8][4096][64]
    u16* kt = (u16*)(ws + 329216 + 4194304);           // 4 MB
    u16* vbf = (u16*)(ws + 329216 + 8388608);          // 16 MB [8][256][4096]
    float* Shf = (float*)(ws + 329216 + 25165824);     // 32 B  [8]

    k_prep<<<320, 256, 0, stream>>>(Wq, bq, Wk, bk, Wv, bv, Whi, Wlo, bias);
    k_proj<<<512, 256, 0, stream>>>(x, Whi, Wlo, bias, qt, kt, vbf);
    k_bound<<<8, 256, 0, stream>>>(qt, kt, Shf);
    k_attn<<<512, 256, 0, stream>>>(qt, kt, vbf, Shf, x, gamma, (float*)d_out);
}